// Round 9
// baseline (351.489 us; speedup 1.0000x reference)
//
#include <hip/hip_runtime.h>

#define THREADS 256
#define SCAN_ITEMS 8    // 2048 elements per scan block
#define NSB 128         // sort blocks: run length E/NSB = 12500 edges
#define BKT_MAX 3200    // >= ceil(N/32)
#define CHUNK 1024      // agg staging chunk (edges); bucket mean 512, sigma ~23

typedef float f32x4 __attribute__((ext_vector_type(4)));
typedef __bf16 bf16x8 __attribute__((ext_vector_type(8)));
typedef int intx4 __attribute__((ext_vector_type(4)));

__device__ inline unsigned short f32_to_bf16_rne(float f) {
    unsigned int u = __float_as_uint(f);
    unsigned int r = u + 0x7fffu + ((u >> 16) & 1u);
    return (unsigned short)(r >> 16);
}
__device__ inline float bf16_bits_to_f32(unsigned short h) {
    return __uint_as_float(((unsigned int)h) << 16);
}
__device__ inline uint4 pack8(const unsigned short* s) {
    uint4 u;
    u.x = (unsigned int)s[0] | ((unsigned int)s[1] << 16);
    u.y = (unsigned int)s[2] | ((unsigned int)s[3] << 16);
    u.z = (unsigned int)s[4] | ((unsigned int)s[5] << 16);
    u.w = (unsigned int)s[6] | ((unsigned int)s[7] << 16);
    return u;
}

// async global->LDS DMA, 16B per lane. LDS dest must be wave-uniform base +
// lane*16 (linear); global src may be per-lane.
__device__ inline void gld_lds16(const void* g, void* l) {
    __builtin_amdgcn_global_load_lds(
        (const __attribute__((address_space(1))) void*)g,
        (__attribute__((address_space(3))) void*)l, 16, 0, 0);
}

// wave 0: exclusive prefix of bsums[0..nb) -> lbase[] (LDS). Caller barriers.
__device__ inline void scan_bsums(const int* __restrict__ bsums, int nb,
                                  int* lbase, int tid) {
    if (tid < 64) {
        int carry = 0;
        for (int base = 0; base < nb; base += 64) {
            int i = base + tid;
            int v = (i < nb) ? bsums[i] : 0;
            int x = v;
#pragma unroll
            for (int s = 1; s < 64; s <<= 1) {
                int y = __shfl_up(x, s);
                if (tid >= s) x += y;
            }
            if (i < nb) lbase[i] = carry + x - v;
            carry += __shfl(x, 63);
        }
    }
}

// ---------------- fused prep: hist (blocks 0..NSB-1) + weight swizzle
// (NSB..NSB+31) + x->bf16 cvt (rest). ----------
__global__ __launch_bounds__(256) void prep(
    const int* __restrict__ dst, int* __restrict__ hist, int E, int nbkt, int chunk,
    const float4* __restrict__ x4, ushort4* __restrict__ xb4, int n4,
    const float* __restrict__ Wn0, const float* __restrict__ Wr0, uint4* __restrict__ Wsw0,
    const float* __restrict__ Wn1, const float* __restrict__ Wr1, uint4* __restrict__ Wsw1) {
    __shared__ int lh[BKT_MAX];
    const int tid = threadIdx.x, blk = blockIdx.x;
    if (blk < NSB) {
        for (int i = tid; i < nbkt; i += 256) lh[i] = 0;
        __syncthreads();
        int s = blk * chunk, e = s + chunk; if (e > E) e = E;
        int n4e = (e > s) ? ((e - s) >> 2) : 0;
        const intx4* d4p = (const intx4*)(dst + s);
        for (int i = tid; i < n4e; i += 256) {
            intx4 d4 = d4p[i];
#pragma unroll
            for (int k = 0; k < 4; k++) atomicAdd(&lh[d4[k] >> 5], 1);
        }
        for (int j = s + (n4e << 2) + tid; j < e; j += 256) atomicAdd(&lh[dst[j] >> 5], 1);
        __syncthreads();
        for (int i = tid; i < nbkt; i += 256) hist[i * NSB + blk] = lh[i];
    } else if (blk < NSB + 32) {
        int b2 = blk - NSB;
        const float* Wn = (b2 < 16) ? Wn0 : Wn1;
        const float* Wr = (b2 < 16) ? Wr0 : Wr1;
        uint4* out = (b2 < 16) ? Wsw0 : Wsw1;
        int id = (b2 & 15) * 256 + tid;
        int lane = id & 63;
        int nt = (id >> 6) & 7;
        int t = id >> 9;
        int kbase = t * 32 + (lane >> 4) * 8;
        int col = nt * 16 + (lane & 15);
        unsigned short hi[8], lo[8];
#pragma unroll
        for (int j = 0; j < 8; j++) {
            int k = kbase + j;
            const float* W = (k < 128) ? (Wn + (size_t)k * 128) : (Wr + (size_t)(k - 128) * 128);
            float v = W[col];
            unsigned short h = f32_to_bf16_rne(v);
            hi[j] = h;
            lo[j] = f32_to_bf16_rne(v - bf16_bits_to_f32(h));
        }
        out[(size_t)((t * 8 + nt) * 2 + 0) * 64 + lane] = pack8(hi);
        out[(size_t)((t * 8 + nt) * 2 + 1) * 64 + lane] = pack8(lo);
    } else {
        int i = (blk - NSB - 32) * 256 + tid;
        if (i < n4) {
            float4 v = x4[i];
            ushort4 r;
            r.x = f32_to_bf16_rne(v.x);
            r.y = f32_to_bf16_rne(v.y);
            r.z = f32_to_bf16_rne(v.z);
            r.w = f32_to_bf16_rne(v.w);
            xb4[i] = r;
        }
    }
}

__global__ void scan1_kernel(const int* __restrict__ cnt, int* __restrict__ off,
                             int* __restrict__ bsums, int n) {
    __shared__ int sdata[THREADS];
    int base = blockIdx.x * (THREADS * SCAN_ITEMS) + threadIdx.x * SCAN_ITEMS;
    int vals[SCAN_ITEMS];
    int tsum = 0;
#pragma unroll
    for (int k = 0; k < SCAN_ITEMS; k++) {
        int idx = base + k;
        int v = (idx < n) ? cnt[idx] : 0;
        vals[k] = tsum;
        tsum += v;
    }
    sdata[threadIdx.x] = tsum;
    __syncthreads();
    for (int s = 1; s < THREADS; s <<= 1) {
        int y = (threadIdx.x >= (unsigned)s) ? sdata[threadIdx.x - s] : 0;
        __syncthreads();
        sdata[threadIdx.x] += y;
        __syncthreads();
    }
    int texcl = sdata[threadIdx.x] - tsum;
#pragma unroll
    for (int k = 0; k < SCAN_ITEMS; k++) {
        int idx = base + k;
        if (idx < n) off[idx] = texcl + vals[k];
    }
    if (threadIdx.x == THREADS - 1) bsums[blockIdx.x] = sdata[THREADS - 1];
}

// Pass 2: stable scatter into bucket-grouped array. The cross-block scan of
// bsums is recomputed locally by wave 0 (<=200 elements, race-free: kernel
// boundary orders bsums) — no scan2 launch. Payload: (src*256)|(dst_local<<25).
__global__ __launch_bounds__(256) void scatter32(const int* __restrict__ src,
                                                 const int* __restrict__ dst,
                                                 const int* __restrict__ hstS,
                                                 const int* __restrict__ bsums, int nbv,
                                                 int* __restrict__ esrt,
                                                 int E, int nbkt, int chunk) {
    __shared__ int cur[BKT_MAX];
    __shared__ int lbase[256];
    const int tid = threadIdx.x, blk = blockIdx.x;
    scan_bsums(bsums, nbv, lbase, tid);
    __syncthreads();
    for (int i = tid; i < nbkt; i += 256) {
        int j = i * NSB + blk;
        cur[i] = hstS[j] + lbase[j >> 11];
    }
    __syncthreads();
    int s = blk * chunk, e = s + chunk; if (e > E) e = E;
    if ((((size_t)dst | (size_t)src) & 15) == 0) {
        int n4 = (e > s) ? ((e - s) >> 2) : 0;
        const intx4* d4p = (const intx4*)(dst + s);
        const intx4* s4p = (const intx4*)(src + s);
        for (int i = tid; i < n4; i += 256) {
            intx4 d4 = d4p[i];
            intx4 s4 = s4p[i];
#pragma unroll
            for (int k = 0; k < 4; k++) {
                int d = d4[k];
                int p = atomicAdd(&cur[d >> 5], 1);
                esrt[p] = (s4[k] << 8) | ((d & 31) << 25);
            }
        }
        for (int j = s + (n4 << 2) + tid; j < e; j += 256) {
            int d = dst[j];
            int p = atomicAdd(&cur[d >> 5], 1);
            esrt[p] = (src[j] << 8) | ((d & 31) << 25);
        }
    } else {
        for (int j = s + tid; j < e; j += 256) {
            int d = dst[j];
            int p = atomicAdd(&cur[d >> 5], 1);
            esrt[p] = (src[j] << 8) | ((d & 31) << 25);
        }
    }
}

// ---------------- bucketed aggregation: LDS sort + ping-pong dword gather ----
// Best-measured agg (65.5us, R7). The gather is at the memory-system delivery
// wall (~6.5 TB/s demand; FETCH 175MB = 8x XCD L2 re-fetch amplification of
// the 25.6MB table, L3-served) — invariant across R1-R5 shape experiments.
__global__ __launch_bounds__(256) void agg_bucket(const unsigned short* __restrict__ hb,
                                                  const int* __restrict__ hstS,
                                                  const int* __restrict__ bsums, int nbv,
                                                  const int* __restrict__ esrt,
                                                  unsigned short* __restrict__ aggb,
                                                  int E, int nbkt, int n) {
    __shared__ int stage[CHUNK];
    __shared__ int sorted[CHUNK];
    __shared__ int cnt[32];
    __shared__ int coff[33];
    __shared__ int lbase[256];
    const int tid = threadIdx.x, lane = tid & 63, w = tid >> 6;
    const int b = blockIdx.x;

    scan_bsums(bsums, nbv, lbase, tid);
    __syncthreads();

    int j0 = b * NSB;
    const int p0 = hstS[j0] + lbase[j0 >> 11];
    int p1 = E;
    if (b + 1 < nbkt) {
        int j1 = (b + 1) * NSB;
        p1 = hstS[j1] + lbase[j1 >> 11];
    }
    const char* hbB = (const char*)hb;

    if (p1 - p0 <= CHUNK) {
        // ---- sort chunk into LDS ----
        int m = p1 - p0;
        for (int i = tid; i < m; i += 256) stage[i] = esrt[p0 + i];
        if (tid < 32) cnt[tid] = 0;
        __syncthreads();
        for (int i = tid; i < m; i += 256) atomicAdd(&cnt[stage[i] >> 25], 1);
        __syncthreads();
        if (tid < 32) {
            int v = cnt[tid];
            int x = v;
#pragma unroll
            for (int s = 1; s < 32; s <<= 1) {
                int y = __shfl_up(x, s);
                if (lane >= s) x += y;
            }
            coff[tid + 1] = x;
            if (tid == 0) coff[0] = 0;
            cnt[tid] = x - v;
        }
        __syncthreads();
        for (int i = tid; i < m; i += 256) {
            int pk = stage[i];
            int p = atomicAdd(&cnt[pk >> 25], 1);
            sorted[p] = pk;
        }
        __syncthreads();

        // ---- per-wave node offsets into registers (no LDS in flush path) ----
        int no[9];
#pragma unroll
        for (int i = 0; i <= 8; i++) no[i] = coff[w * 8 + i];
        const int s = no[0], e2 = no[8];
        const int w8 = w * 8;
        int curL = 0;               // local node in [0,8]
        float ax = 0.f, ay = 0.f;

        auto flushTo = [&](int tgt) {
            while (curL < tgt) {
                int node = b * 32 + w8 + curL;
                int d = no[curL + 1] - no[curL];
                float inv = 1.0f / (float)(d > 1 ? d : 1);
                unsigned int o = (unsigned int)f32_to_bf16_rne(ax * inv)
                               | ((unsigned int)f32_to_bf16_rne(ay * inv) << 16);
                if (node < n)
                    *(unsigned int*)((char*)aggb + (size_t)node * 256 + lane * 4) = o;
                ax = 0.f; ay = 0.f; ++curL;
            }
        };
        auto issue = [&](unsigned int* v, int* nd, int base) {
#pragma unroll
            for (int j = 0; j < 8; j++) {
                int pk = sorted[base + j];              // broadcast LDS read
                nd[j] = (pk >> 25) - w8;                // local node target
                v[j] = *(const unsigned int*)(hbB + (unsigned)(pk & 0x01FFFF00) + lane * 4);
            }
        };
        auto consume = [&](const unsigned int* v, const int* nd) {
#pragma unroll
            for (int j = 0; j < 8; j++) {
                flushTo(nd[j]);
                ax += __uint_as_float(v[j] << 16);
                ay += __uint_as_float(v[j] & 0xffff0000u);
            }
        };

        const int nb8 = (e2 - s) >> 3;
        unsigned int vA[8], vB[8];
        int ndA[8], ndB[8];
        if (nb8 > 0) {
            issue(vA, ndA, s);
            int k = 1;
            for (; k + 1 < nb8; k += 2) {
                issue(vB, ndB, s + k * 8);
                consume(vA, ndA);
                issue(vA, ndA, s + k * 8 + 8);
                consume(vB, ndB);
            }
            if (k < nb8) {
                issue(vB, ndB, s + k * 8);
                consume(vA, ndA);
                consume(vB, ndB);
            } else {
                consume(vA, ndA);
            }
        }
        for (int i = s + (nb8 << 3); i < e2; i++) {
            int pk = sorted[i];
            flushTo((pk >> 25) - w8);
            unsigned int vv = *(const unsigned int*)(hbB + (unsigned)(pk & 0x01FFFF00) + lane * 4);
            ax += __uint_as_float(vv << 16);
            ay += __uint_as_float(vv & 0xffff0000u);
        }
        flushTo(8);
        return;
    }

    // ---- fallback: multi-chunk bucket ----
    float accx[8], accy[8];
    int dcnt[8];
#pragma unroll
    for (int nl = 0; nl < 8; nl++) { accx[nl] = 0.f; accy[nl] = 0.f; dcnt[nl] = 0; }
    for (int base = p0; base < p1; base += CHUNK) {
        int m = p1 - base; if (m > CHUNK) m = CHUNK;
        for (int i = tid; i < m; i += 256) stage[i] = esrt[base + i];
        if (tid < 32) cnt[tid] = 0;
        __syncthreads();
        for (int i = tid; i < m; i += 256) atomicAdd(&cnt[stage[i] >> 25], 1);
        __syncthreads();
        if (tid < 32) {
            int v = cnt[tid];
            int x = v;
#pragma unroll
            for (int s = 1; s < 32; s <<= 1) {
                int y = __shfl_up(x, s);
                if (lane >= s) x += y;
            }
            coff[tid + 1] = x;
            if (tid == 0) coff[0] = 0;
            cnt[tid] = x - v;
        }
        __syncthreads();
        for (int i = tid; i < m; i += 256) {
            int pk = stage[i];
            int p = atomicAdd(&cnt[pk >> 25], 1);
            sorted[p] = pk;
        }
        __syncthreads();
#pragma unroll
        for (int nl = 0; nl < 8; nl++) {
            int node_l = w * 8 + nl;
            int s = coff[node_l], e2 = coff[node_l + 1];
            dcnt[nl] += e2 - s;
            float ax = accx[nl], ay = accy[nl];
            int i = s;
            for (; i + 8 <= e2; i += 8) {
                unsigned int v[8];
#pragma unroll
                for (int j = 0; j < 8; j++) {
                    unsigned off = (unsigned)(sorted[i + j] & 0x01FFFF00);
                    v[j] = *(const unsigned int*)(hbB + off + lane * 4);
                }
#pragma unroll
                for (int j = 0; j < 8; j++) {
                    ax += __uint_as_float(v[j] << 16);
                    ay += __uint_as_float(v[j] & 0xffff0000u);
                }
            }
            for (; i < e2; i++) {
                unsigned off = (unsigned)(sorted[i] & 0x01FFFF00);
                unsigned int vv = *(const unsigned int*)(hbB + off + lane * 4);
                ax += __uint_as_float(vv << 16);
                ay += __uint_as_float(vv & 0xffff0000u);
            }
            accx[nl] = ax; accy[nl] = ay;
        }
        __syncthreads();
    }
#pragma unroll
    for (int nl = 0; nl < 8; nl++) {
        int node = b * 32 + w * 8 + nl;
        if (node < n) {
            int d = dcnt[nl];
            float inv = 1.0f / (float)(d > 1 ? d : 1);
            unsigned int o = (unsigned int)f32_to_bf16_rne(accx[nl] * inv)
                           | ((unsigned int)f32_to_bf16_rne(accy[nl] * inv) << 16);
            *(unsigned int*)(aggb + (size_t)node * 128 + lane * 2) = o;
        }
    }
}

// ---------------- fused SAGE update via split-bf16 MFMA ----------------
// Staging via async global_load_lds DMA: W always (linear lane-ordered copy);
// A for bf16 pass-through chunks (byte-identity copy + address swizzle folded
// into the per-lane GLOBAL address, LDS dest linear — m173 pattern). The f32
// hi/lo split (layer 0, c>=2, x source) keeps the guarded VALU path. OOB rows
// in DMA'd chunks read workspace garbage into discarded output rows (MFMA is
// row-independent). Layer 1 has no lo-fragments: compact Alds (16KB) -> LDS
// 48KB -> 3 blocks/CU (768/782 blocks resident in one round).
template <int LAYER, bool FINAL>
__global__ __launch_bounds__(256, (LAYER == 0) ? 2 : 3) void update_mfma(
    const unsigned short* __restrict__ aggb, const void* __restrict__ hsrc,
    const uint4* __restrict__ Wsw, const float* __restrict__ bias,
    unsigned short* __restrict__ hout,
    const float* __restrict__ Wh, const float* __restrict__ bh,
    float* __restrict__ logits, int n) {
    constexpr int AF = (LAYER == 0) ? 2 : 1;   // hi/lo slot factor
    __shared__ uint4 Alds[1024 * AF];
    __shared__ uint4 Wlds[2048];
    const int tid = threadIdx.x;
    const int lane = tid & 63;
    const int w = tid >> 6;
    const int i0 = blockIdx.x * 128;

    f32x4 acc[2][8];
#pragma unroll
    for (int mt = 0; mt < 2; mt++)
#pragma unroll
        for (int nt = 0; nt < 8; nt++) acc[mt][nt] = (f32x4)0.f;

    const int r = tid >> 1;
    const int half = tid & 1;
    const int rg = i0 + r;
    const bool inb = rg < n;
    const int mt_s = r >> 4;
    const int lidx = r & 15;

    for (int c = 0; c < 4; c++) {
        const bool haslo = (LAYER == 0 && c >= 2);
        {   // async W stage: 8 x 16B DMA per thread, overlaps A stage below
            const uint4* srcW = Wsw + (size_t)c * 2048;
#pragma unroll
            for (int g = 0; g < 8; g++)
                gld_lds16(srcW + g * 256 + tid, &Wlds[g * 256 + tid]);
        }
        if (!haslo) {
            // async A stage: entry e of frag (m16,kt) holds row (m16*16+(e&15)),
            // 16B at byte cc*128 + kt*64 + (e>>4)*16 — identical bytes to the
            // old repack path, swizzle moved to the global address.
            const unsigned short* bsrc = (c < 2) ? aggb : (const unsigned short*)hsrc;
            const int cc = (c < 2) ? c : c - 2;
#pragma unroll
            for (int blk = 0; blk < 4; blk++) {
                int G = blk * 256 + tid;
                int e = G & 63;
                int fidx = G >> 6;                       // m16*2 + kt
                int row = i0 + ((fidx >> 1) << 4) + (e & 15);
                const char* g = (const char*)bsrc + (size_t)row * 256
                              + cc * 128 + (fidx & 1) * 64 + (e >> 4) * 16;
                gld_lds16(g, &Alds[fidx * (64 * AF) + e]);
            }
        } else {
            // f32 source (x): hi/lo split on VALU, bounds-guarded
            unsigned short hiA[32], loA[32];
            const float4* s4 = (const float4*)((const float*)hsrc + (size_t)rg * 128 +
                                               (c - 2) * 64 + half * 32);
#pragma unroll
            for (int q = 0; q < 8; q++) {
                float4 f = inb ? s4[q] : make_float4(0.f, 0.f, 0.f, 0.f);
                float vv[4] = {f.x, f.y, f.z, f.w};
#pragma unroll
                for (int e = 0; e < 4; e++) {
                    unsigned short h = f32_to_bf16_rne(vv[e]);
                    hiA[q * 4 + e] = h;
                    loA[q * 4 + e] = f32_to_bf16_rne(vv[e] - bf16_bits_to_f32(h));
                }
            }
            unsigned int baseHi = (unsigned)(mt_s * 2 + half) * (64 * AF);
#pragma unroll
            for (int g2 = 0; g2 < 4; g2++) {
                Alds[baseHi + lidx + 16 * g2] = pack8(&hiA[g2 * 8]);
                Alds[baseHi + 64 + lidx + 16 * g2] = pack8(&loA[g2 * 8]);
            }
        }
        __syncthreads();
#pragma unroll
        for (int kt = 0; kt < 2; kt++) {
            bf16x8 a0h = *(const bf16x8*)&Alds[((w * 2 + 0) * 2 + kt) * (64 * AF) + lane];
            bf16x8 a1h = *(const bf16x8*)&Alds[((w * 2 + 1) * 2 + kt) * (64 * AF) + lane];
            bf16x8 a0l, a1l;
            if (haslo) {
                a0l = *(const bf16x8*)&Alds[((w * 2 + 0) * 2 + kt) * (64 * AF) + 64 + lane];
                a1l = *(const bf16x8*)&Alds[((w * 2 + 1) * 2 + kt) * (64 * AF) + 64 + lane];
            }
#pragma unroll
            for (int nt = 0; nt < 8; nt++) {
                bf16x8 bhv = *(const bf16x8*)&Wlds[((kt * 8 + nt) * 2 + 0) * 64 + lane];
                bf16x8 blv = *(const bf16x8*)&Wlds[((kt * 8 + nt) * 2 + 1) * 64 + lane];
                acc[0][nt] = __builtin_amdgcn_mfma_f32_16x16x32_bf16(a0h, bhv, acc[0][nt], 0, 0, 0);
                acc[0][nt] = __builtin_amdgcn_mfma_f32_16x16x32_bf16(a0h, blv, acc[0][nt], 0, 0, 0);
                acc[1][nt] = __builtin_amdgcn_mfma_f32_16x16x32_bf16(a1h, bhv, acc[1][nt], 0, 0, 0);
                acc[1][nt] = __builtin_amdgcn_mfma_f32_16x16x32_bf16(a1h, blv, acc[1][nt], 0, 0, 0);
                if (haslo) {
                    acc[0][nt] = __builtin_amdgcn_mfma_f32_16x16x32_bf16(a0l, bhv, acc[0][nt], 0, 0, 0);
                    acc[1][nt] = __builtin_amdgcn_mfma_f32_16x16x32_bf16(a1l, bhv, acc[1][nt], 0, 0, 0);
                }
            }
        }
        __syncthreads();
    }

    const int col = lane & 15;
    const int g4 = lane >> 4;
    float bcol[8];
#pragma unroll
    for (int nt = 0; nt < 8; nt++) bcol[nt] = bias[nt * 16 + col];
    if (!FINAL) {
#pragma unroll
        for (int mt = 0; mt < 2; mt++) {
            int nodeBase = i0 + (w * 2 + mt) * 16 + g4 * 4;
#pragma unroll
            for (int reg = 0; reg < 4; reg++) {
                int node = nodeBase + reg;
                if (node < n) {
#pragma unroll
                    for (int nt = 0; nt < 8; nt++) {
                        float v = acc[mt][nt][reg] + bcol[nt];
                        v = v > 0.f ? v : 0.f;
                        hout[(size_t)node * 128 + nt * 16 + col] = f32_to_bf16_rne(v);
                    }
                }
            }
        }
    } else {
        float whc[8];
#pragma unroll
        for (int nt = 0; nt < 8; nt++) whc[nt] = Wh[nt * 16 + col];
        float bhv = bh[0];
#pragma unroll
        for (int mt = 0; mt < 2; mt++) {
            int nodeBase = i0 + (w * 2 + mt) * 16 + g4 * 4;
#pragma unroll
            for (int reg = 0; reg < 4; reg++) {
                float s = 0.f;
#pragma unroll
                for (int nt = 0; nt < 8; nt++) {
                    float v = acc[mt][nt][reg] + bcol[nt];
                    v = v > 0.f ? v : 0.f;
                    s += v * whc[nt];
                }
                s += __shfl_xor(s, 1);
                s += __shfl_xor(s, 2);
                s += __shfl_xor(s, 4);
                s += __shfl_xor(s, 8);
                int node = nodeBase + reg;
                if (col == 0 && node < n) logits[node] = s + bhv;
            }
        }
    }
}

extern "C" void kernel_launch(void* const* d_in, const int* in_sizes, int n_in,
                              void* d_out, int out_size, void* d_ws, size_t ws_size,
                              hipStream_t stream) {
    const float* x   = (const float*)d_in[0];
    const int*   ei  = (const int*)d_in[1];
    const float* Wn0 = (const float*)d_in[2];
    const float* Wr0 = (const float*)d_in[3];
    const float* b0  = (const float*)d_in[4];
    const float* Wn1 = (const float*)d_in[5];
    const float* Wr1 = (const float*)d_in[6];
    const float* b1  = (const float*)d_in[7];
    const float* Wh  = (const float*)d_in[8];
    const float* bh  = (const float*)d_in[9];
    float* logits = (float*)d_out;

    int N = in_sizes[0] / 128;
    int E = in_sizes[1] / 2;
    const int* src = ei;
    const int* dst = ei + E;

    int nbkt = (N + 31) >> 5;                       // 32-node coarse buckets
    int HS = nbkt * NSB;                            // histogram entries
    int NB = (HS + 2047) / 2048;                    // scan1 blocks (<=256)
    int chunk = (((E + NSB - 1) / NSB) + 3) & ~3;   // multiple of 4 for int4 path

    char* ws = (char*)d_ws;
    size_t cur = 0;
    auto alloc = [&](size_t bytes) -> void* {
        void* p = ws + cur;
        cur += (bytes + 255) & ~(size_t)255;
        return p;
    };
    int* hist  = (int*)alloc((size_t)HS * 4);
    int* bsums = (int*)alloc((size_t)NB * 4);
    int* esrt  = (int*)alloc((size_t)E * 4);
    unsigned short* xb  = (unsigned short*)alloc((size_t)N * 128 * 2);
    unsigned short* h0b = (unsigned short*)alloc((size_t)N * 128 * 2);
    unsigned short* agb = (unsigned short*)alloc((size_t)N * 128 * 2);
    uint4* Wsw0 = (uint4*)alloc(131072);
    uint4* Wsw1 = (uint4*)alloc(131072);
    (void)ws_size; (void)n_in; (void)out_size;

    // fused prep: hist + weight swizzle + x->bf16 cvt (one launch)
    int n4 = N * 32;
    int gPrep = NSB + 32 + (n4 + 255) / 256;
    hipLaunchKernelGGL(prep, dim3(gPrep), dim3(256), 0, stream,
                       dst, hist, E, nbkt, chunk,
                       (const float4*)x, (ushort4*)xb, n4,
                       Wn0, Wr0, Wsw0, Wn1, Wr1, Wsw1);

    // scan (block-sums consumed by local rescans downstream) + scatter
    hipLaunchKernelGGL(scan1_kernel,  dim3(NB),  dim3(256), 0, stream, hist, hist, bsums, HS);
    hipLaunchKernelGGL(scatter32,     dim3(NSB), dim3(256), 0, stream, src, dst, hist, bsums, NB, esrt, E, nbkt, chunk);

    int gUpd = (N + 127) / 128;

    // Layer 0
    hipLaunchKernelGGL(agg_bucket, dim3(nbkt), dim3(256), 0, stream, xb, hist, bsums, NB, esrt, agb, E, nbkt, N);
    hipLaunchKernelGGL((update_mfma<0, false>), dim3(gUpd), dim3(256), 0, stream,
                       agb, (const void*)x, Wsw0, b0, h0b, nullptr, nullptr, nullptr, N);
    // Layer 1 + fused head
    hipLaunchKernelGGL(agg_bucket, dim3(nbkt), dim3(256), 0, stream, h0b, hist, bsums, NB, esrt, agb, E, nbkt, N);
    hipLaunchKernelGGL((update_mfma<1, true>), dim3(gUpd), dim3(256), 0, stream,
                       agb, (const void*)h0b, Wsw1, b1, nullptr, Wh, bh, logits, N);
}

// Round 10
// 344.098 us; speedup vs baseline: 1.0215x; 1.0215x over previous
//
#include <hip/hip_runtime.h>

#define THREADS 256
#define SCAN_ITEMS 8    // 2048 elements per scan block
#define NSB 128         // sort blocks: run length E/NSB = 12500 edges
#define BKT_MAX 3200    // >= ceil(N/32)
#define CHUNK 1024      // agg staging chunk (edges); bucket mean 512, sigma ~23

typedef float f32x4 __attribute__((ext_vector_type(4)));
typedef __bf16 bf16x8 __attribute__((ext_vector_type(8)));
typedef int intx4 __attribute__((ext_vector_type(4)));

__device__ inline unsigned short f32_to_bf16_rne(float f) {
    unsigned int u = __float_as_uint(f);
    unsigned int r = u + 0x7fffu + ((u >> 16) & 1u);
    return (unsigned short)(r >> 16);
}
__device__ inline float bf16_bits_to_f32(unsigned short h) {
    return __uint_as_float(((unsigned int)h) << 16);
}
__device__ inline uint4 pack8(const unsigned short* s) {
    uint4 u;
    u.x = (unsigned int)s[0] | ((unsigned int)s[1] << 16);
    u.y = (unsigned int)s[2] | ((unsigned int)s[3] << 16);
    u.z = (unsigned int)s[4] | ((unsigned int)s[5] << 16);
    u.w = (unsigned int)s[6] | ((unsigned int)s[7] << 16);
    return u;
}

// ---------------- fused prep: hist (blocks 0..NSB-1) + weight swizzle
// (NSB..NSB+31) + x->bf16 cvt (rest). ----------
__global__ __launch_bounds__(256) void prep(
    const int* __restrict__ dst, int* __restrict__ hist, int E, int nbkt, int chunk,
    const float4* __restrict__ x4, ushort4* __restrict__ xb4, int n4,
    const float* __restrict__ Wn0, const float* __restrict__ Wr0, uint4* __restrict__ Wsw0,
    const float* __restrict__ Wn1, const float* __restrict__ Wr1, uint4* __restrict__ Wsw1) {
    __shared__ int lh[BKT_MAX];
    const int tid = threadIdx.x, blk = blockIdx.x;
    if (blk < NSB) {
        for (int i = tid; i < nbkt; i += 256) lh[i] = 0;
        __syncthreads();
        int s = blk * chunk, e = s + chunk; if (e > E) e = E;
        int n4e = (e > s) ? ((e - s) >> 2) : 0;
        const intx4* d4p = (const intx4*)(dst + s);
        for (int i = tid; i < n4e; i += 256) {
            intx4 d4 = d4p[i];
#pragma unroll
            for (int k = 0; k < 4; k++) atomicAdd(&lh[d4[k] >> 5], 1);
        }
        for (int j = s + (n4e << 2) + tid; j < e; j += 256) atomicAdd(&lh[dst[j] >> 5], 1);
        __syncthreads();
        for (int i = tid; i < nbkt; i += 256) hist[i * NSB + blk] = lh[i];
    } else if (blk < NSB + 32) {
        int b2 = blk - NSB;
        const float* Wn = (b2 < 16) ? Wn0 : Wn1;
        const float* Wr = (b2 < 16) ? Wr0 : Wr1;
        uint4* out = (b2 < 16) ? Wsw0 : Wsw1;
        int id = (b2 & 15) * 256 + tid;
        int lane = id & 63;
        int nt = (id >> 6) & 7;
        int t = id >> 9;
        int kbase = t * 32 + (lane >> 4) * 8;
        int col = nt * 16 + (lane & 15);
        unsigned short hi[8], lo[8];
#pragma unroll
        for (int j = 0; j < 8; j++) {
            int k = kbase + j;
            const float* W = (k < 128) ? (Wn + (size_t)k * 128) : (Wr + (size_t)(k - 128) * 128);
            float v = W[col];
            unsigned short h = f32_to_bf16_rne(v);
            hi[j] = h;
            lo[j] = f32_to_bf16_rne(v - bf16_bits_to_f32(h));
        }
        out[(size_t)((t * 8 + nt) * 2 + 0) * 64 + lane] = pack8(hi);
        out[(size_t)((t * 8 + nt) * 2 + 1) * 64 + lane] = pack8(lo);
    } else {
        int i = (blk - NSB - 32) * 256 + tid;
        if (i < n4) {
            float4 v = x4[i];
            ushort4 r;
            r.x = f32_to_bf16_rne(v.x);
            r.y = f32_to_bf16_rne(v.y);
            r.z = f32_to_bf16_rne(v.z);
            r.w = f32_to_bf16_rne(v.w);
            xb4[i] = r;
        }
    }
}

__global__ void scan1_kernel(const int* __restrict__ cnt, int* __restrict__ off,
                             int* __restrict__ bsums, int n) {
    __shared__ int sdata[THREADS];
    int base = blockIdx.x * (THREADS * SCAN_ITEMS) + threadIdx.x * SCAN_ITEMS;
    int vals[SCAN_ITEMS];
    int tsum = 0;
#pragma unroll
    for (int k = 0; k < SCAN_ITEMS; k++) {
        int idx = base + k;
        int v = (idx < n) ? cnt[idx] : 0;
        vals[k] = tsum;
        tsum += v;
    }
    sdata[threadIdx.x] = tsum;
    __syncthreads();
    for (int s = 1; s < THREADS; s <<= 1) {
        int y = (threadIdx.x >= (unsigned)s) ? sdata[threadIdx.x - s] : 0;
        __syncthreads();
        sdata[threadIdx.x] += y;
        __syncthreads();
    }
    int texcl = sdata[threadIdx.x] - tsum;
#pragma unroll
    for (int k = 0; k < SCAN_ITEMS; k++) {
        int idx = base + k;
        if (idx < n) off[idx] = texcl + vals[k];
    }
    if (threadIdx.x == THREADS - 1) bsums[blockIdx.x] = sdata[THREADS - 1];
}

// Wave-parallel block-sum scan.
__global__ void scan2_wave(const int* __restrict__ bsums, int* __restrict__ bbase,
                           int nb, int* __restrict__ offN) {
    const int lane = threadIdx.x;   // 64 threads, 1 block
    int carry = 0;
    for (int base = 0; base < nb; base += 64) {
        int i = base + lane;
        int v = (i < nb) ? bsums[i] : 0;
        int x = v;
#pragma unroll
        for (int s = 1; s < 64; s <<= 1) {
            int y = __shfl_up(x, s);
            if (lane >= s) x += y;
        }
        if (i < nb) bbase[i] = carry + x - v;
        carry += __shfl(x, 63);
    }
    if (lane == 0) *offN = carry;
}

// Pass 2: stable scatter into bucket-grouped array. bbase folded in at cursor
// load (no scan3b pass). Payload: (src*256) | (dst_local << 25).
__global__ __launch_bounds__(256) void scatter32(const int* __restrict__ src,
                                                 const int* __restrict__ dst,
                                                 const int* __restrict__ hstS,
                                                 const int* __restrict__ bbase,
                                                 int* __restrict__ esrt,
                                                 int E, int nbkt, int chunk) {
    __shared__ int cur[BKT_MAX];
    const int tid = threadIdx.x, blk = blockIdx.x;
    for (int i = tid; i < nbkt; i += 256) {
        int j = i * NSB + blk;
        cur[i] = hstS[j] + bbase[j >> 11];
    }
    __syncthreads();
    int s = blk * chunk, e = s + chunk; if (e > E) e = E;
    if ((((size_t)dst | (size_t)src) & 15) == 0) {
        int n4 = (e > s) ? ((e - s) >> 2) : 0;
        const intx4* d4p = (const intx4*)(dst + s);
        const intx4* s4p = (const intx4*)(src + s);
        for (int i = tid; i < n4; i += 256) {
            intx4 d4 = d4p[i];
            intx4 s4 = s4p[i];
#pragma unroll
            for (int k = 0; k < 4; k++) {
                int d = d4[k];
                int p = atomicAdd(&cur[d >> 5], 1);
                esrt[p] = (s4[k] << 8) | ((d & 31) << 25);
            }
        }
        for (int j = s + (n4 << 2) + tid; j < e; j += 256) {
            int d = dst[j];
            int p = atomicAdd(&cur[d >> 5], 1);
            esrt[p] = (src[j] << 8) | ((d & 31) << 25);
        }
    } else {
        for (int j = s + tid; j < e; j += 256) {
            int d = dst[j];
            int p = atomicAdd(&cur[d >> 5], 1);
            esrt[p] = (src[j] << 8) | ((d & 31) << 25);
        }
    }
}

// ---------------- bucketed aggregation: LDS sort + ping-pong dword gather ----
// Best-measured agg (65.5-66.4us, R7/R8). The gather is at the memory-system
// delivery wall (~6.5 TB/s demand; FETCH 175MB = 8x XCD L2 re-fetch
// amplification of the 25.6MB table, L3-served) — closed, do not re-litigate.
__global__ __launch_bounds__(256) void agg_bucket(const unsigned short* __restrict__ hb,
                                                  const int* __restrict__ hstS,
                                                  const int* __restrict__ bbase,
                                                  const int* __restrict__ esrt,
                                                  unsigned short* __restrict__ aggb,
                                                  int E, int nbkt, int n) {
    __shared__ int stage[CHUNK];
    __shared__ int sorted[CHUNK];
    __shared__ int cnt[32];
    __shared__ int coff[33];
    const int tid = threadIdx.x, lane = tid & 63, w = tid >> 6;
    const int b = blockIdx.x;

    int j0 = b * NSB;
    const int p0 = hstS[j0] + bbase[j0 >> 11];
    int p1 = E;
    if (b + 1 < nbkt) {
        int j1 = (b + 1) * NSB;
        p1 = hstS[j1] + bbase[j1 >> 11];
    }
    const char* hbB = (const char*)hb;

    if (p1 - p0 <= CHUNK) {
        // ---- sort chunk into LDS ----
        int m = p1 - p0;
        for (int i = tid; i < m; i += 256) stage[i] = esrt[p0 + i];
        if (tid < 32) cnt[tid] = 0;
        __syncthreads();
        for (int i = tid; i < m; i += 256) atomicAdd(&cnt[stage[i] >> 25], 1);
        __syncthreads();
        if (tid < 32) {
            int v = cnt[tid];
            int x = v;
#pragma unroll
            for (int s = 1; s < 32; s <<= 1) {
                int y = __shfl_up(x, s);
                if (lane >= s) x += y;
            }
            coff[tid + 1] = x;
            if (tid == 0) coff[0] = 0;
            cnt[tid] = x - v;
        }
        __syncthreads();
        for (int i = tid; i < m; i += 256) {
            int pk = stage[i];
            int p = atomicAdd(&cnt[pk >> 25], 1);
            sorted[p] = pk;
        }
        __syncthreads();

        // ---- per-wave node offsets into registers (no LDS in flush path) ----
        int no[9];
#pragma unroll
        for (int i = 0; i <= 8; i++) no[i] = coff[w * 8 + i];
        const int s = no[0], e2 = no[8];
        const int w8 = w * 8;
        int curL = 0;               // local node in [0,8]
        float ax = 0.f, ay = 0.f;

        auto flushTo = [&](int tgt) {
            while (curL < tgt) {
                int node = b * 32 + w8 + curL;
                int d = no[curL + 1] - no[curL];
                float inv = 1.0f / (float)(d > 1 ? d : 1);
                unsigned int o = (unsigned int)f32_to_bf16_rne(ax * inv)
                               | ((unsigned int)f32_to_bf16_rne(ay * inv) << 16);
                if (node < n)
                    *(unsigned int*)((char*)aggb + (size_t)node * 256 + lane * 4) = o;
                ax = 0.f; ay = 0.f; ++curL;
            }
        };
        auto issue = [&](unsigned int* v, int* nd, int base) {
#pragma unroll
            for (int j = 0; j < 8; j++) {
                int pk = sorted[base + j];              // broadcast LDS read
                nd[j] = (pk >> 25) - w8;                // local node target
                v[j] = *(const unsigned int*)(hbB + (unsigned)(pk & 0x01FFFF00) + lane * 4);
            }
        };
        auto consume = [&](const unsigned int* v, const int* nd) {
#pragma unroll
            for (int j = 0; j < 8; j++) {
                flushTo(nd[j]);
                ax += __uint_as_float(v[j] << 16);
                ay += __uint_as_float(v[j] & 0xffff0000u);
            }
        };

        const int nb8 = (e2 - s) >> 3;
        unsigned int vA[8], vB[8];
        int ndA[8], ndB[8];
        if (nb8 > 0) {
            issue(vA, ndA, s);
            int k = 1;
            for (; k + 1 < nb8; k += 2) {
                issue(vB, ndB, s + k * 8);
                consume(vA, ndA);
                issue(vA, ndA, s + k * 8 + 8);
                consume(vB, ndB);
            }
            if (k < nb8) {
                issue(vB, ndB, s + k * 8);
                consume(vA, ndA);
                consume(vB, ndB);
            } else {
                consume(vA, ndA);
            }
        }
        for (int i = s + (nb8 << 3); i < e2; i++) {
            int pk = sorted[i];
            flushTo((pk >> 25) - w8);
            unsigned int vv = *(const unsigned int*)(hbB + (unsigned)(pk & 0x01FFFF00) + lane * 4);
            ax += __uint_as_float(vv << 16);
            ay += __uint_as_float(vv & 0xffff0000u);
        }
        flushTo(8);
        return;
    }

    // ---- fallback: multi-chunk bucket ----
    float accx[8], accy[8];
    int dcnt[8];
#pragma unroll
    for (int nl = 0; nl < 8; nl++) { accx[nl] = 0.f; accy[nl] = 0.f; dcnt[nl] = 0; }
    for (int base = p0; base < p1; base += CHUNK) {
        int m = p1 - base; if (m > CHUNK) m = CHUNK;
        for (int i = tid; i < m; i += 256) stage[i] = esrt[base + i];
        if (tid < 32) cnt[tid] = 0;
        __syncthreads();
        for (int i = tid; i < m; i += 256) atomicAdd(&cnt[stage[i] >> 25], 1);
        __syncthreads();
        if (tid < 32) {
            int v = cnt[tid];
            int x = v;
#pragma unroll
            for (int s = 1; s < 32; s <<= 1) {
                int y = __shfl_up(x, s);
                if (lane >= s) x += y;
            }
            coff[tid + 1] = x;
            if (tid == 0) coff[0] = 0;
            cnt[tid] = x - v;
        }
        __syncthreads();
        for (int i = tid; i < m; i += 256) {
            int pk = stage[i];
            int p = atomicAdd(&cnt[pk >> 25], 1);
            sorted[p] = pk;
        }
        __syncthreads();
#pragma unroll
        for (int nl = 0; nl < 8; nl++) {
            int node_l = w * 8 + nl;
            int s = coff[node_l], e2 = coff[node_l + 1];
            dcnt[nl] += e2 - s;
            float ax = accx[nl], ay = accy[nl];
            int i = s;
            for (; i + 8 <= e2; i += 8) {
                unsigned int v[8];
#pragma unroll
                for (int j = 0; j < 8; j++) {
                    unsigned off = (unsigned)(sorted[i + j] & 0x01FFFF00);
                    v[j] = *(const unsigned int*)(hbB + off + lane * 4);
                }
#pragma unroll
                for (int j = 0; j < 8; j++) {
                    ax += __uint_as_float(v[j] << 16);
                    ay += __uint_as_float(v[j] & 0xffff0000u);
                }
            }
            for (; i < e2; i++) {
                unsigned off = (unsigned)(sorted[i] & 0x01FFFF00);
                unsigned int vv = *(const unsigned int*)(hbB + off + lane * 4);
                ax += __uint_as_float(vv << 16);
                ay += __uint_as_float(vv & 0xffff0000u);
            }
            accx[nl] = ax; accy[nl] = ay;
        }
        __syncthreads();
    }
#pragma unroll
    for (int nl = 0; nl < 8; nl++) {
        int node = b * 32 + w * 8 + nl;
        if (node < n) {
            int d = dcnt[nl];
            float inv = 1.0f / (float)(d > 1 ? d : 1);
            unsigned int o = (unsigned int)f32_to_bf16_rne(accx[nl] * inv)
                           | ((unsigned int)f32_to_bf16_rne(accy[nl] * inv) << 16);
            *(unsigned int*)(aggb + (size_t)node * 128 + lane * 2) = o;
        }
    }
}

// ---------------- fused SAGE update via split-bf16 MFMA ----------------
// R8's VALU-staged version (Wlds staging load-bearing per R7; DMA staging
// regressed in R9). Single isolated change vs R8: layer 1 has no lo-fragments,
// so Alds shrinks to 16KB (AF=1) -> LDS 48KB -> 3 blocks/CU.
template <int LAYER, bool FINAL>
__global__ __launch_bounds__(256, (LAYER == 0) ? 2 : 3) void update_mfma(
    const unsigned short* __restrict__ aggb, const void* __restrict__ hsrc,
    const uint4* __restrict__ Wsw, const float* __restrict__ bias,
    unsigned short* __restrict__ hout,
    const float* __restrict__ Wh, const float* __restrict__ bh,
    float* __restrict__ logits, int n) {
    constexpr int AF = (LAYER == 0) ? 2 : 1;   // hi/lo slot factor
    __shared__ uint4 Alds[1024 * AF];
    __shared__ uint4 Wlds[2048];
    const int tid = threadIdx.x;
    const int lane = tid & 63;
    const int w = tid >> 6;
    const int i0 = blockIdx.x * 128;

    f32x4 acc[2][8];
#pragma unroll
    for (int mt = 0; mt < 2; mt++)
#pragma unroll
        for (int nt = 0; nt < 8; nt++) acc[mt][nt] = (f32x4)0.f;

    const int r = tid >> 1;
    const int half = tid & 1;
    const int rg = i0 + r;
    const bool inb = rg < n;
    const int mt_s = r >> 4;
    const int lidx = r & 15;

    for (int c = 0; c < 4; c++) {
        const bool haslo = (LAYER == 0 && c >= 2);
        {
            const uint4* srcW = Wsw + (size_t)c * 2048;
#pragma unroll
            for (int g = 0; g < 8; g++) Wlds[g * 256 + tid] = srcW[g * 256 + tid];
        }
        {
            unsigned short hiA[32], loA[32];
            if (LAYER == 0 && c >= 2) {
                const float4* s4 = (const float4*)((const float*)hsrc + (size_t)rg * 128 +
                                                   (c - 2) * 64 + half * 32);
#pragma unroll
                for (int q = 0; q < 8; q++) {
                    float4 f = inb ? s4[q] : make_float4(0.f, 0.f, 0.f, 0.f);
                    float vv[4] = {f.x, f.y, f.z, f.w};
#pragma unroll
                    for (int e = 0; e < 4; e++) {
                        unsigned short h = f32_to_bf16_rne(vv[e]);
                        hiA[q * 4 + e] = h;
                        loA[q * 4 + e] = f32_to_bf16_rne(vv[e] - bf16_bits_to_f32(h));
                    }
                }
            } else {
                const unsigned short* bsrc = (c < 2) ? aggb : (const unsigned short*)hsrc;
                int cc = (c < 2) ? c : c - 2;
                const uint4* s4 = (const uint4*)(bsrc + (size_t)rg * 128 + cc * 64 + half * 32);
#pragma unroll
                for (int q = 0; q < 4; q++) {
                    uint4 u = inb ? s4[q] : make_uint4(0, 0, 0, 0);
                    unsigned int uu[4] = {u.x, u.y, u.z, u.w};
#pragma unroll
                    for (int e = 0; e < 4; e++) {
                        hiA[q * 8 + e * 2 + 0] = (unsigned short)(uu[e] & 0xffffu);
                        hiA[q * 8 + e * 2 + 1] = (unsigned short)(uu[e] >> 16);
                    }
                }
            }
            unsigned int baseHi = (unsigned)(mt_s * 2 + half) * (64 * AF);
#pragma unroll
            for (int g2 = 0; g2 < 4; g2++)
                Alds[baseHi + lidx + 16 * g2] = pack8(&hiA[g2 * 8]);
            if (haslo) {
#pragma unroll
                for (int g2 = 0; g2 < 4; g2++)
                    Alds[baseHi + 64 + lidx + 16 * g2] = pack8(&loA[g2 * 8]);
            }
        }
        __syncthreads();
#pragma unroll
        for (int kt = 0; kt < 2; kt++) {
            bf16x8 a0h = *(const bf16x8*)&Alds[((w * 2 + 0) * 2 + kt) * (64 * AF) + lane];
            bf16x8 a1h = *(const bf16x8*)&Alds[((w * 2 + 1) * 2 + kt) * (64 * AF) + lane];
            bf16x8 a0l, a1l;
            if (haslo) {
                a0l = *(const bf16x8*)&Alds[((w * 2 + 0) * 2 + kt) * (64 * AF) + 64 + lane];
                a1l = *(const bf16x8*)&Alds[((w * 2 + 1) * 2 + kt) * (64 * AF) + 64 + lane];
            }
#pragma unroll
            for (int nt = 0; nt < 8; nt++) {
                bf16x8 bhv = *(const bf16x8*)&Wlds[((kt * 8 + nt) * 2 + 0) * 64 + lane];
                bf16x8 blv = *(const bf16x8*)&Wlds[((kt * 8 + nt) * 2 + 1) * 64 + lane];
                acc[0][nt] = __builtin_amdgcn_mfma_f32_16x16x32_bf16(a0h, bhv, acc[0][nt], 0, 0, 0);
                acc[0][nt] = __builtin_amdgcn_mfma_f32_16x16x32_bf16(a0h, blv, acc[0][nt], 0, 0, 0);
                acc[1][nt] = __builtin_amdgcn_mfma_f32_16x16x32_bf16(a1h, bhv, acc[1][nt], 0, 0, 0);
                acc[1][nt] = __builtin_amdgcn_mfma_f32_16x16x32_bf16(a1h, blv, acc[1][nt], 0, 0, 0);
                if (haslo) {
                    acc[0][nt] = __builtin_amdgcn_mfma_f32_16x16x32_bf16(a0l, bhv, acc[0][nt], 0, 0, 0);
                    acc[1][nt] = __builtin_amdgcn_mfma_f32_16x16x32_bf16(a1l, bhv, acc[1][nt], 0, 0, 0);
                }
            }
        }
        __syncthreads();
    }

    const int col = lane & 15;
    const int g4 = lane >> 4;
    float bcol[8];
#pragma unroll
    for (int nt = 0; nt < 8; nt++) bcol[nt] = bias[nt * 16 + col];
    if (!FINAL) {
#pragma unroll
        for (int mt = 0; mt < 2; mt++) {
            int nodeBase = i0 + (w * 2 + mt) * 16 + g4 * 4;
#pragma unroll
            for (int reg = 0; reg < 4; reg++) {
                int node = nodeBase + reg;
                if (node < n) {
#pragma unroll
                    for (int nt = 0; nt < 8; nt++) {
                        float v = acc[mt][nt][reg] + bcol[nt];
                        v = v > 0.f ? v : 0.f;
                        hout[(size_t)node * 128 + nt * 16 + col] = f32_to_bf16_rne(v);
                    }
                }
            }
        }
    } else {
        float whc[8];
#pragma unroll
        for (int nt = 0; nt < 8; nt++) whc[nt] = Wh[nt * 16 + col];
        float bhv = bh[0];
#pragma unroll
        for (int mt = 0; mt < 2; mt++) {
            int nodeBase = i0 + (w * 2 + mt) * 16 + g4 * 4;
#pragma unroll
            for (int reg = 0; reg < 4; reg++) {
                float s = 0.f;
#pragma unroll
                for (int nt = 0; nt < 8; nt++) {
                    float v = acc[mt][nt][reg] + bcol[nt];
                    v = v > 0.f ? v : 0.f;
                    s += v * whc[nt];
                }
                s += __shfl_xor(s, 1);
                s += __shfl_xor(s, 2);
                s += __shfl_xor(s, 4);
                s += __shfl_xor(s, 8);
                int node = nodeBase + reg;
                if (col == 0 && node < n) logits[node] = s + bhv;
            }
        }
    }
}

extern "C" void kernel_launch(void* const* d_in, const int* in_sizes, int n_in,
                              void* d_out, int out_size, void* d_ws, size_t ws_size,
                              hipStream_t stream) {
    const float* x   = (const float*)d_in[0];
    const int*   ei  = (const int*)d_in[1];
    const float* Wn0 = (const float*)d_in[2];
    const float* Wr0 = (const float*)d_in[3];
    const float* b0  = (const float*)d_in[4];
    const float* Wn1 = (const float*)d_in[5];
    const float* Wr1 = (const float*)d_in[6];
    const float* b1  = (const float*)d_in[7];
    const float* Wh  = (const float*)d_in[8];
    const float* bh  = (const float*)d_in[9];
    float* logits = (float*)d_out;

    int N = in_sizes[0] / 128;
    int E = in_sizes[1] / 2;
    const int* src = ei;
    const int* dst = ei + E;

    int nbkt = (N + 31) >> 5;                       // 32-node coarse buckets
    int HS = nbkt * NSB;                            // histogram entries
    int NB = (HS + 2047) / 2048;                    // scan1 blocks
    int chunk = (((E + NSB - 1) / NSB) + 3) & ~3;   // multiple of 4 for int4 path

    char* ws = (char*)d_ws;
    size_t cur = 0;
    auto alloc = [&](size_t bytes) -> void* {
        void* p = ws + cur;
        cur += (bytes + 255) & ~(size_t)255;
        return p;
    };
    int* hist  = (int*)alloc((size_t)HS * 4);
    int* bsums = (int*)alloc((size_t)NB * 4);
    int* bbase = (int*)alloc((size_t)NB * 4);
    int* scrat = (int*)alloc(256);
    int* esrt  = (int*)alloc((size_t)E * 4);
    unsigned short* xb  = (unsigned short*)alloc((size_t)N * 128 * 2);
    unsigned short* h0b = (unsigned short*)alloc((size_t)N * 128 * 2);
    unsigned short* agb = (unsigned short*)alloc((size_t)N * 128 * 2);
    uint4* Wsw0 = (uint4*)alloc(131072);
    uint4* Wsw1 = (uint4*)alloc(131072);
    (void)ws_size; (void)n_in; (void)out_size;

    // fused prep: hist + weight swizzle + x->bf16 cvt (one launch)
    int n4 = N * 32;
    int gPrep = NSB + 32 + (n4 + 255) / 256;
    hipLaunchKernelGGL(prep, dim3(gPrep), dim3(256), 0, stream,
                       dst, hist, E, nbkt, chunk,
                       (const float4*)x, (ushort4*)xb, n4,
                       Wn0, Wr0, Wsw0, Wn1, Wr1, Wsw1);

    // scan chain (scan3b folded into consumers) + scatter
    hipLaunchKernelGGL(scan1_kernel,  dim3(NB),  dim3(256), 0, stream, hist, hist, bsums, HS);
    hipLaunchKernelGGL(scan2_wave,    dim3(1),   dim3(64),  0, stream, bsums, bbase, NB, scrat);
    hipLaunchKernelGGL(scatter32,     dim3(NSB), dim3(256), 0, stream, src, dst, hist, bbase, esrt, E, nbkt, chunk);

    int gUpd = (N + 127) / 128;

    // Layer 0
    hipLaunchKernelGGL(agg_bucket, dim3(nbkt), dim3(256), 0, stream, xb, hist, bbase, esrt, agb, E, nbkt, N);
    hipLaunchKernelGGL((update_mfma<0, false>), dim3(gUpd), dim3(256), 0, stream,
                       agb, (const void*)x, Wsw0, b0, h0b, nullptr, nullptr, nullptr, N);
    // Layer 1 + fused head
    hipLaunchKernelGGL(agg_bucket, dim3(nbkt), dim3(256), 0, stream, h0b, hist, bbase, esrt, agb, E, nbkt, N);
    hipLaunchKernelGGL((update_mfma<1, true>), dim3(gUpd), dim3(256), 0, stream,
                       agb, (const void*)h0b, Wsw1, b1, nullptr, Wh, bh, logits, N);
}

// Round 11
// 298.326 us; speedup vs baseline: 1.1782x; 1.1534x over previous
//
#include <hip/hip_runtime.h>

#define THREADS 256
#define SCAN_ITEMS 8    // 2048 elements per scan block
#define NSB 128         // sort blocks: run length E/NSB = 12500 edges
#define BKT_MAX 3200    // >= ceil(N/32)
#define CHUNK 1024      // agg staging chunk (edges); bucket mean 512, sigma ~23

typedef float f32x4 __attribute__((ext_vector_type(4)));
typedef float floatx2 __attribute__((ext_vector_type(2)));
typedef __bf16 bf16x8 __attribute__((ext_vector_type(8)));
typedef int intx4 __attribute__((ext_vector_type(4)));

__device__ inline unsigned short f32_to_bf16_rne(float f) {
    unsigned int u = __float_as_uint(f);
    unsigned int r = u + 0x7fffu + ((u >> 16) & 1u);
    return (unsigned short)(r >> 16);
}
__device__ inline float bf16_bits_to_f32(unsigned short h) {
    return __uint_as_float(((unsigned int)h) << 16);
}
__device__ inline uint4 pack8(const unsigned short* s) {
    uint4 u;
    u.x = (unsigned int)s[0] | ((unsigned int)s[1] << 16);
    u.y = (unsigned int)s[2] | ((unsigned int)s[3] << 16);
    u.z = (unsigned int)s[4] | ((unsigned int)s[5] << 16);
    u.w = (unsigned int)s[6] | ((unsigned int)s[7] << 16);
    return u;
}
// OCP e4m3 HW converts (gfx940+): pack 2 f32 -> 2 fp8 bytes / unpack 2 fp8 -> 2 f32
__device__ inline unsigned int pk_fp8(float a, float b) {
    return (unsigned int)__builtin_amdgcn_cvt_pk_fp8_f32(a, b, 0, false);
}
__device__ inline floatx2 unpk_fp8(unsigned int u) {
    return __builtin_amdgcn_cvt_pk_f32_fp8(u, false);
}

// ---------------- fused prep: hist (blocks 0..NSB-1) + weight swizzle
// (NSB..NSB+31) + x->fp8 cvt (rest; gather table is e4m3, root path reads
// f32 x directly so only the neighbor-mean term sees fp8 rounding). --------
__global__ __launch_bounds__(256) void prep(
    const int* __restrict__ dst, int* __restrict__ hist, int E, int nbkt, int chunk,
    const float4* __restrict__ x4, unsigned int* __restrict__ xq4, int n4,
    const float* __restrict__ Wn0, const float* __restrict__ Wr0, uint4* __restrict__ Wsw0,
    const float* __restrict__ Wn1, const float* __restrict__ Wr1, uint4* __restrict__ Wsw1) {
    __shared__ int lh[BKT_MAX];
    const int tid = threadIdx.x, blk = blockIdx.x;
    if (blk < NSB) {
        for (int i = tid; i < nbkt; i += 256) lh[i] = 0;
        __syncthreads();
        int s = blk * chunk, e = s + chunk; if (e > E) e = E;
        int n4e = (e > s) ? ((e - s) >> 2) : 0;
        const intx4* d4p = (const intx4*)(dst + s);
        for (int i = tid; i < n4e; i += 256) {
            intx4 d4 = d4p[i];
#pragma unroll
            for (int k = 0; k < 4; k++) atomicAdd(&lh[d4[k] >> 5], 1);
        }
        for (int j = s + (n4e << 2) + tid; j < e; j += 256) atomicAdd(&lh[dst[j] >> 5], 1);
        __syncthreads();
        for (int i = tid; i < nbkt; i += 256) hist[i * NSB + blk] = lh[i];
    } else if (blk < NSB + 32) {
        int b2 = blk - NSB;
        const float* Wn = (b2 < 16) ? Wn0 : Wn1;
        const float* Wr = (b2 < 16) ? Wr0 : Wr1;
        uint4* out = (b2 < 16) ? Wsw0 : Wsw1;
        int id = (b2 & 15) * 256 + tid;
        int lane = id & 63;
        int nt = (id >> 6) & 7;
        int t = id >> 9;
        int kbase = t * 32 + (lane >> 4) * 8;
        int col = nt * 16 + (lane & 15);
        unsigned short hi[8], lo[8];
#pragma unroll
        for (int j = 0; j < 8; j++) {
            int k = kbase + j;
            const float* W = (k < 128) ? (Wn + (size_t)k * 128) : (Wr + (size_t)(k - 128) * 128);
            float v = W[col];
            unsigned short h = f32_to_bf16_rne(v);
            hi[j] = h;
            lo[j] = f32_to_bf16_rne(v - bf16_bits_to_f32(h));
        }
        out[(size_t)((t * 8 + nt) * 2 + 0) * 64 + lane] = pack8(hi);
        out[(size_t)((t * 8 + nt) * 2 + 1) * 64 + lane] = pack8(lo);
    } else {
        int i = (blk - NSB - 32) * 256 + tid;
        if (i < n4) {
            float4 v = x4[i];
            unsigned int u = pk_fp8(v.x, v.y);
            u |= (unsigned int)__builtin_amdgcn_cvt_pk_fp8_f32(v.z, v.w, 0, false) << 16;
            xq4[i] = u;
        }
    }
}

__global__ void scan1_kernel(const int* __restrict__ cnt, int* __restrict__ off,
                             int* __restrict__ bsums, int n) {
    __shared__ int sdata[THREADS];
    int base = blockIdx.x * (THREADS * SCAN_ITEMS) + threadIdx.x * SCAN_ITEMS;
    int vals[SCAN_ITEMS];
    int tsum = 0;
#pragma unroll
    for (int k = 0; k < SCAN_ITEMS; k++) {
        int idx = base + k;
        int v = (idx < n) ? cnt[idx] : 0;
        vals[k] = tsum;
        tsum += v;
    }
    sdata[threadIdx.x] = tsum;
    __syncthreads();
    for (int s = 1; s < THREADS; s <<= 1) {
        int y = (threadIdx.x >= (unsigned)s) ? sdata[threadIdx.x - s] : 0;
        __syncthreads();
        sdata[threadIdx.x] += y;
        __syncthreads();
    }
    int texcl = sdata[threadIdx.x] - tsum;
#pragma unroll
    for (int k = 0; k < SCAN_ITEMS; k++) {
        int idx = base + k;
        if (idx < n) off[idx] = texcl + vals[k];
    }
    if (threadIdx.x == THREADS - 1) bsums[blockIdx.x] = sdata[THREADS - 1];
}

// Wave-parallel block-sum scan.
__global__ void scan2_wave(const int* __restrict__ bsums, int* __restrict__ bbase,
                           int nb, int* __restrict__ offN) {
    const int lane = threadIdx.x;   // 64 threads, 1 block
    int carry = 0;
    for (int base = 0; base < nb; base += 64) {
        int i = base + lane;
        int v = (i < nb) ? bsums[i] : 0;
        int x = v;
#pragma unroll
        for (int s = 1; s < 64; s <<= 1) {
            int y = __shfl_up(x, s);
            if (lane >= s) x += y;
        }
        if (i < nb) bbase[i] = carry + x - v;
        carry += __shfl(x, 63);
    }
    if (lane == 0) *offN = carry;
}

// Pass 2: stable scatter into bucket-grouped array. bbase folded in at cursor
// load. Payload: (src*128) | (dst_local << 25) — fp8 rows are 128B, so the
// byte offset of the source row lives in bits [23:7].
__global__ __launch_bounds__(256) void scatter32(const int* __restrict__ src,
                                                 const int* __restrict__ dst,
                                                 const int* __restrict__ hstS,
                                                 const int* __restrict__ bbase,
                                                 int* __restrict__ esrt,
                                                 int E, int nbkt, int chunk) {
    __shared__ int cur[BKT_MAX];
    const int tid = threadIdx.x, blk = blockIdx.x;
    for (int i = tid; i < nbkt; i += 256) {
        int j = i * NSB + blk;
        cur[i] = hstS[j] + bbase[j >> 11];
    }
    __syncthreads();
    int s = blk * chunk, e = s + chunk; if (e > E) e = E;
    if ((((size_t)dst | (size_t)src) & 15) == 0) {
        int n4 = (e > s) ? ((e - s) >> 2) : 0;
        const intx4* d4p = (const intx4*)(dst + s);
        const intx4* s4p = (const intx4*)(src + s);
        for (int i = tid; i < n4; i += 256) {
            intx4 d4 = d4p[i];
            intx4 s4 = s4p[i];
#pragma unroll
            for (int k = 0; k < 4; k++) {
                int d = d4[k];
                int p = atomicAdd(&cur[d >> 5], 1);
                esrt[p] = (s4[k] << 7) | ((d & 31) << 25);
            }
        }
        for (int j = s + (n4 << 2) + tid; j < e; j += 256) {
            int d = dst[j];
            int p = atomicAdd(&cur[d >> 5], 1);
            esrt[p] = (src[j] << 7) | ((d & 31) << 25);
        }
    } else {
        for (int j = s + tid; j < e; j += 256) {
            int d = dst[j];
            int p = atomicAdd(&cur[d >> 5], 1);
            esrt[p] = (src[j] << 7) | ((d & 31) << 25);
        }
    }
}

// ---------------- bucketed aggregation: LDS sort + ping-pong fp8 gather ----
// Same structure as the 66us bf16 version (R7/R8); rows are now 128B fp8 —
// half the demand bytes against the ~6.5 TB/s delivery wall. Each lane loads
// a ushort (2 fp8 = dims 2*lane, 2*lane+1) and unpacks with v_cvt_pk_f32_fp8.
// Accumulation f32, output bf16 (unchanged downstream).
__global__ __launch_bounds__(256) void agg_bucket(const unsigned char* __restrict__ hb,
                                                  const int* __restrict__ hstS,
                                                  const int* __restrict__ bbase,
                                                  const int* __restrict__ esrt,
                                                  unsigned short* __restrict__ aggb,
                                                  int E, int nbkt, int n) {
    __shared__ int stage[CHUNK];
    __shared__ int sorted[CHUNK];
    __shared__ int cnt[32];
    __shared__ int coff[33];
    const int tid = threadIdx.x, lane = tid & 63, w = tid >> 6;
    const int b = blockIdx.x;

    int j0 = b * NSB;
    const int p0 = hstS[j0] + bbase[j0 >> 11];
    int p1 = E;
    if (b + 1 < nbkt) {
        int j1 = (b + 1) * NSB;
        p1 = hstS[j1] + bbase[j1 >> 11];
    }
    const char* hbB = (const char*)hb;

    if (p1 - p0 <= CHUNK) {
        // ---- sort chunk into LDS ----
        int m = p1 - p0;
        for (int i = tid; i < m; i += 256) stage[i] = esrt[p0 + i];
        if (tid < 32) cnt[tid] = 0;
        __syncthreads();
        for (int i = tid; i < m; i += 256) atomicAdd(&cnt[stage[i] >> 25], 1);
        __syncthreads();
        if (tid < 32) {
            int v = cnt[tid];
            int x = v;
#pragma unroll
            for (int s = 1; s < 32; s <<= 1) {
                int y = __shfl_up(x, s);
                if (lane >= s) x += y;
            }
            coff[tid + 1] = x;
            if (tid == 0) coff[0] = 0;
            cnt[tid] = x - v;
        }
        __syncthreads();
        for (int i = tid; i < m; i += 256) {
            int pk = stage[i];
            int p = atomicAdd(&cnt[pk >> 25], 1);
            sorted[p] = pk;
        }
        __syncthreads();

        // ---- per-wave node offsets into registers (no LDS in flush path) ----
        int no[9];
#pragma unroll
        for (int i = 0; i <= 8; i++) no[i] = coff[w * 8 + i];
        const int s = no[0], e2 = no[8];
        const int w8 = w * 8;
        int curL = 0;               // local node in [0,8]
        float ax = 0.f, ay = 0.f;

        auto flushTo = [&](int tgt) {
            while (curL < tgt) {
                int node = b * 32 + w8 + curL;
                int d = no[curL + 1] - no[curL];
                float inv = 1.0f / (float)(d > 1 ? d : 1);
                unsigned int o = (unsigned int)f32_to_bf16_rne(ax * inv)
                               | ((unsigned int)f32_to_bf16_rne(ay * inv) << 16);
                if (node < n)
                    *(unsigned int*)((char*)aggb + (size_t)node * 256 + lane * 4) = o;
                ax = 0.f; ay = 0.f; ++curL;
            }
        };
        auto issue = [&](unsigned int* v, int* nd, int base) {
#pragma unroll
            for (int j = 0; j < 8; j++) {
                int pk = sorted[base + j];              // broadcast LDS read
                nd[j] = (pk >> 25) - w8;                // local node target
                v[j] = *(const unsigned short*)(hbB + (unsigned)(pk & 0x00FFFF80) + lane * 2);
            }
        };
        auto consume = [&](const unsigned int* v, const int* nd) {
#pragma unroll
            for (int j = 0; j < 8; j++) {
                flushTo(nd[j]);
                floatx2 f = unpk_fp8(v[j]);
                ax += f.x;
                ay += f.y;
            }
        };

        const int nb8 = (e2 - s) >> 3;
        unsigned int vA[8], vB[8];
        int ndA[8], ndB[8];
        if (nb8 > 0) {
            issue(vA, ndA, s);
            int k = 1;
            for (; k + 1 < nb8; k += 2) {
                issue(vB, ndB, s + k * 8);
                consume(vA, ndA);
                issue(vA, ndA, s + k * 8 + 8);
                consume(vB, ndB);
            }
            if (k < nb8) {
                issue(vB, ndB, s + k * 8);
                consume(vA, ndA);
                consume(vB, ndB);
            } else {
                consume(vA, ndA);
            }
        }
        for (int i = s + (nb8 << 3); i < e2; i++) {
            int pk = sorted[i];
            flushTo((pk >> 25) - w8);
            unsigned int vv = *(const unsigned short*)(hbB + (unsigned)(pk & 0x00FFFF80) + lane * 2);
            floatx2 f = unpk_fp8(vv);
            ax += f.x;
            ay += f.y;
        }
        flushTo(8);
        return;
    }

    // ---- fallback: multi-chunk bucket ----
    float accx[8], accy[8];
    int dcnt[8];
#pragma unroll
    for (int nl = 0; nl < 8; nl++) { accx[nl] = 0.f; accy[nl] = 0.f; dcnt[nl] = 0; }
    for (int base = p0; base < p1; base += CHUNK) {
        int m = p1 - base; if (m > CHUNK) m = CHUNK;
        for (int i = tid; i < m; i += 256) stage[i] = esrt[base + i];
        if (tid < 32) cnt[tid] = 0;
        __syncthreads();
        for (int i = tid; i < m; i += 256) atomicAdd(&cnt[stage[i] >> 25], 1);
        __syncthreads();
        if (tid < 32) {
            int v = cnt[tid];
            int x = v;
#pragma unroll
            for (int s = 1; s < 32; s <<= 1) {
                int y = __shfl_up(x, s);
                if (lane >= s) x += y;
            }
            coff[tid + 1] = x;
            if (tid == 0) coff[0] = 0;
            cnt[tid] = x - v;
        }
        __syncthreads();
        for (int i = tid; i < m; i += 256) {
            int pk = stage[i];
            int p = atomicAdd(&cnt[pk >> 25], 1);
            sorted[p] = pk;
        }
        __syncthreads();
#pragma unroll
        for (int nl = 0; nl < 8; nl++) {
            int node_l = w * 8 + nl;
            int s = coff[node_l], e2 = coff[node_l + 1];
            dcnt[nl] += e2 - s;
            float ax = accx[nl], ay = accy[nl];
            int i = s;
            for (; i + 8 <= e2; i += 8) {
                unsigned int v[8];
#pragma unroll
                for (int j = 0; j < 8; j++) {
                    unsigned off = (unsigned)(sorted[i + j] & 0x00FFFF80);
                    v[j] = *(const unsigned short*)(hbB + off + lane * 2);
                }
#pragma unroll
                for (int j = 0; j < 8; j++) {
                    floatx2 f = unpk_fp8(v[j]);
                    ax += f.x;
                    ay += f.y;
                }
            }
            for (; i < e2; i++) {
                unsigned off = (unsigned)(sorted[i] & 0x00FFFF80);
                unsigned int vv = *(const unsigned short*)(hbB + off + lane * 2);
                floatx2 f = unpk_fp8(vv);
                ax += f.x;
                ay += f.y;
            }
            accx[nl] = ax; accy[nl] = ay;
        }
        __syncthreads();
    }
#pragma unroll
    for (int nl = 0; nl < 8; nl++) {
        int node = b * 32 + w * 8 + nl;
        if (node < n) {
            int d = dcnt[nl];
            float inv = 1.0f / (float)(d > 1 ? d : 1);
            unsigned int o = (unsigned int)f32_to_bf16_rne(accx[nl] * inv)
                           | ((unsigned int)f32_to_bf16_rne(accy[nl] * inv) << 16);
            *(unsigned int*)(aggb + (size_t)node * 128 + lane * 2) = o;
        }
    }
}

// ---------------- fused SAGE update via split-bf16 MFMA ----------------
// R8's proven form (Wlds staging load-bearing; (256,2) both layers). Layer 0
// additionally emits h0 in fp8 (houtq) for layer 1's gather table.
template <int LAYER, bool FINAL>
__global__ __launch_bounds__(256, 2) void update_mfma(
    const unsigned short* __restrict__ aggb, const void* __restrict__ hsrc,
    const uint4* __restrict__ Wsw, const float* __restrict__ bias,
    unsigned short* __restrict__ hout, unsigned char* __restrict__ houtq,
    const float* __restrict__ Wh, const float* __restrict__ bh,
    float* __restrict__ logits, int n) {
    __shared__ uint4 Alds[2048];
    __shared__ uint4 Wlds[2048];
    const int tid = threadIdx.x;
    const int lane = tid & 63;
    const int w = tid >> 6;
    const int i0 = blockIdx.x * 128;

    f32x4 acc[2][8];
#pragma unroll
    for (int mt = 0; mt < 2; mt++)
#pragma unroll
        for (int nt = 0; nt < 8; nt++) acc[mt][nt] = (f32x4)0.f;

    const int r = tid >> 1;
    const int half = tid & 1;
    const int rg = i0 + r;
    const bool inb = rg < n;
    const int mt_s = r >> 4;
    const int lidx = r & 15;

    for (int c = 0; c < 4; c++) {
        const bool haslo = (LAYER == 0 && c >= 2);
        {
            const uint4* srcW = Wsw + (size_t)c * 2048;
#pragma unroll
            for (int g = 0; g < 8; g++) Wlds[g * 256 + tid] = srcW[g * 256 + tid];
        }
        {
            unsigned short hiA[32], loA[32];
            if (LAYER == 0 && c >= 2) {
                const float4* s4 = (const float4*)((const float*)hsrc + (size_t)rg * 128 +
                                                   (c - 2) * 64 + half * 32);
#pragma unroll
                for (int q = 0; q < 8; q++) {
                    float4 f = inb ? s4[q] : make_float4(0.f, 0.f, 0.f, 0.f);
                    float vv[4] = {f.x, f.y, f.z, f.w};
#pragma unroll
                    for (int e = 0; e < 4; e++) {
                        unsigned short h = f32_to_bf16_rne(vv[e]);
                        hiA[q * 4 + e] = h;
                        loA[q * 4 + e] = f32_to_bf16_rne(vv[e] - bf16_bits_to_f32(h));
                    }
                }
            } else {
                const unsigned short* bsrc = (c < 2) ? aggb : (const unsigned short*)hsrc;
                int cc = (c < 2) ? c : c - 2;
                const uint4* s4 = (const uint4*)(bsrc + (size_t)rg * 128 + cc * 64 + half * 32);
#pragma unroll
                for (int q = 0; q < 4; q++) {
                    uint4 u = inb ? s4[q] : make_uint4(0, 0, 0, 0);
                    unsigned int uu[4] = {u.x, u.y, u.z, u.w};
#pragma unroll
                    for (int e = 0; e < 4; e++) {
                        hiA[q * 8 + e * 2 + 0] = (unsigned short)(uu[e] & 0xffffu);
                        hiA[q * 8 + e * 2 + 1] = (unsigned short)(uu[e] >> 16);
                    }
                }
            }
            unsigned int baseHi = ((mt_s * 2 + half) * 2 + 0) * 64;
#pragma unroll
            for (int g2 = 0; g2 < 4; g2++)
                Alds[baseHi + lidx + 16 * g2] = pack8(&hiA[g2 * 8]);
            if (haslo) {
#pragma unroll
                for (int g2 = 0; g2 < 4; g2++)
                    Alds[baseHi + 64 + lidx + 16 * g2] = pack8(&loA[g2 * 8]);
            }
        }
        __syncthreads();
#pragma unroll
        for (int kt = 0; kt < 2; kt++) {
            bf16x8 a0h = *(const bf16x8*)&Alds[(((w * 2 + 0) * 2 + kt) * 2 + 0) * 64 + lane];
            bf16x8 a1h = *(const bf16x8*)&Alds[(((w * 2 + 1) * 2 + kt) * 2 + 0) * 64 + lane];
            bf16x8 a0l, a1l;
            if (haslo) {
                a0l = *(const bf16x8*)&Alds[(((w * 2 + 0) * 2 + kt) * 2 + 1) * 64 + lane];
                a1l = *(const bf16x8*)&Alds[(((w * 2 + 1) * 2 + kt) * 2 + 1) * 64 + lane];
            }
#pragma unroll
            for (int nt = 0; nt < 8; nt++) {
                bf16x8 bhv = *(const bf16x8*)&Wlds[((kt * 8 + nt) * 2 + 0) * 64 + lane];
                bf16x8 blv = *(const bf16x8*)&Wlds[((kt * 8 + nt) * 2 + 1) * 64 + lane];
                acc[0][nt] = __builtin_amdgcn_mfma_f32_16x16x32_bf16(a0h, bhv, acc[0][nt], 0, 0, 0);
                acc[0][nt] = __builtin_amdgcn_mfma_f32_16x16x32_bf16(a0h, blv, acc[0][nt], 0, 0, 0);
                acc[1][nt] = __builtin_amdgcn_mfma_f32_16x16x32_bf16(a1h, bhv, acc[1][nt], 0, 0, 0);
                acc[1][nt] = __builtin_amdgcn_mfma_f32_16x16x32_bf16(a1h, blv, acc[1][nt], 0, 0, 0);
                if (haslo) {
                    acc[0][nt] = __builtin_amdgcn_mfma_f32_16x16x32_bf16(a0l, bhv, acc[0][nt], 0, 0, 0);
                    acc[1][nt] = __builtin_amdgcn_mfma_f32_16x16x32_bf16(a1l, bhv, acc[1][nt], 0, 0, 0);
                }
            }
        }
        __syncthreads();
    }

    const int col = lane & 15;
    const int g4 = lane >> 4;
    float bcol[8];
#pragma unroll
    for (int nt = 0; nt < 8; nt++) bcol[nt] = bias[nt * 16 + col];
    if (!FINAL) {
#pragma unroll
        for (int mt = 0; mt < 2; mt++) {
            int nodeBase = i0 + (w * 2 + mt) * 16 + g4 * 4;
#pragma unroll
            for (int reg = 0; reg < 4; reg++) {
                int node = nodeBase + reg;
                if (node < n) {
#pragma unroll
                    for (int nt = 0; nt < 8; nt++) {
                        float v = acc[mt][nt][reg] + bcol[nt];
                        v = v > 0.f ? v : 0.f;
                        hout[(size_t)node * 128 + nt * 16 + col] = f32_to_bf16_rne(v);
                        houtq[(size_t)node * 128 + nt * 16 + col] =
                            (unsigned char)(pk_fp8(v, v) & 0xffu);
                    }
                }
            }
        }
    } else {
        float whc[8];
#pragma unroll
        for (int nt = 0; nt < 8; nt++) whc[nt] = Wh[nt * 16 + col];
        float bhv = bh[0];
#pragma unroll
        for (int mt = 0; mt < 2; mt++) {
            int nodeBase = i0 + (w * 2 + mt) * 16 + g4 * 4;
#pragma unroll
            for (int reg = 0; reg < 4; reg++) {
                float s = 0.f;
#pragma unroll
                for (int nt = 0; nt < 8; nt++) {
                    float v = acc[mt][nt][reg] + bcol[nt];
                    v = v > 0.f ? v : 0.f;
                    s += v * whc[nt];
                }
                s += __shfl_xor(s, 1);
                s += __shfl_xor(s, 2);
                s += __shfl_xor(s, 4);
                s += __shfl_xor(s, 8);
                int node = nodeBase + reg;
                if (col == 0 && node < n) logits[node] = s + bhv;
            }
        }
    }
}

extern "C" void kernel_launch(void* const* d_in, const int* in_sizes, int n_in,
                              void* d_out, int out_size, void* d_ws, size_t ws_size,
                              hipStream_t stream) {
    const float* x   = (const float*)d_in[0];
    const int*   ei  = (const int*)d_in[1];
    const float* Wn0 = (const float*)d_in[2];
    const float* Wr0 = (const float*)d_in[3];
    const float* b0  = (const float*)d_in[4];
    const float* Wn1 = (const float*)d_in[5];
    const float* Wr1 = (const float*)d_in[6];
    const float* b1  = (const float*)d_in[7];
    const float* Wh  = (const float*)d_in[8];
    const float* bh  = (const float*)d_in[9];
    float* logits = (float*)d_out;

    int N = in_sizes[0] / 128;
    int E = in_sizes[1] / 2;
    const int* src = ei;
    const int* dst = ei + E;

    int nbkt = (N + 31) >> 5;                       // 32-node coarse buckets
    int HS = nbkt * NSB;                            // histogram entries
    int NB = (HS + 2047) / 2048;                    // scan1 blocks
    int chunk = (((E + NSB - 1) / NSB) + 3) & ~3;   // multiple of 4 for int4 path

    char* ws = (char*)d_ws;
    size_t cur = 0;
    auto alloc = [&](size_t bytes) -> void* {
        void* p = ws + cur;
        cur += (bytes + 255) & ~(size_t)255;
        return p;
    };
    int* hist  = (int*)alloc((size_t)HS * 4);
    int* bsums = (int*)alloc((size_t)NB * 4);
    int* bbase = (int*)alloc((size_t)NB * 4);
    int* scrat = (int*)alloc(256);
    int* esrt  = (int*)alloc((size_t)E * 4);
    unsigned char* xq  = (unsigned char*)alloc((size_t)N * 128);   // fp8 gather tables
    unsigned char* h0q = (unsigned char*)alloc((size_t)N * 128);
    unsigned short* h0b = (unsigned short*)alloc((size_t)N * 128 * 2);
    unsigned short* agb = (unsigned short*)alloc((size_t)N * 128 * 2);
    uint4* Wsw0 = (uint4*)alloc(131072);
    uint4* Wsw1 = (uint4*)alloc(131072);
    (void)ws_size; (void)n_in; (void)out_size;

    // fused prep: hist + weight swizzle + x->fp8 cvt (one launch)
    int n4 = N * 32;
    int gPrep = NSB + 32 + (n4 + 255) / 256;
    hipLaunchKernelGGL(prep, dim3(gPrep), dim3(256), 0, stream,
                       dst, hist, E, nbkt, chunk,
                       (const float4*)x, (unsigned int*)xq, n4,
                       Wn0, Wr0, Wsw0, Wn1, Wr1, Wsw1);

    // scan chain + scatter
    hipLaunchKernelGGL(scan1_kernel,  dim3(NB),  dim3(256), 0, stream, hist, hist, bsums, HS);
    hipLaunchKernelGGL(scan2_wave,    dim3(1),   dim3(64),  0, stream, bsums, bbase, NB, scrat);
    hipLaunchKernelGGL(scatter32,     dim3(NSB), dim3(256), 0, stream, src, dst, hist, bbase, esrt, E, nbkt, chunk);

    int gUpd = (N + 127) / 128;

    // Layer 0
    hipLaunchKernelGGL(agg_bucket, dim3(nbkt), dim3(256), 0, stream, xq, hist, bbase, esrt, agb, E, nbkt, N);
    hipLaunchKernelGGL((update_mfma<0, false>), dim3(gUpd), dim3(256), 0, stream,
                       agb, (const void*)x, Wsw0, b0, h0b, h0q, nullptr, nullptr, nullptr, N);
    // Layer 1 + fused head
    hipLaunchKernelGGL(agg_bucket, dim3(nbkt), dim3(256), 0, stream, h0q, hist, bbase, esrt, agb, E, nbkt, N);
    hipLaunchKernelGGL((update_mfma<1, true>), dim3(gUpd), dim3(256), 0, stream,
                       agb, (const void*)h0b, Wsw1, b1, nullptr, nullptr, Wh, bh, logits, N);
}